// Round 7
// baseline (55.266 us; speedup 1.0000x reference)
//
#include <hip/hip_runtime.h>
#include <hip/hip_bf16.h>

// B=1, NN=256, C=128, H=4, D=32 — O(N^3) factorization, 3 kernels.
//   k_w:    w = x @ W_w (256x512); also out = bias (for later atomics)
//   k_T:    P,Q,R on the fly; T = P R; Q,P,Rt side-writes; normp partials.
//           grid (8 k-blocks, 16 i-blocks, 4 heads) = 512 blocks, 2 blocks/CU.
//   k_x1x2S: per block (4 rows, head h): rn; S rows = (Q rn) @ Rt (LDS-chunked);
//           wp = P.*S, wq = Q.*T.*rn; x1 = wp v, x2 = wq v; y = x1.*x2;
//           out += y @ W_proj[h-slice] (atomicAdd, bias-init'd by k_w).

constexpr size_t OFF_W     = 0;                    // 256*512
constexpr size_t OFF_P     = 131072;               // 4*65536 each
constexpr size_t OFF_Q     = OFF_P + 262144;
constexpr size_t OFF_RT    = OFF_Q + 262144;       // R^T: [h][k][j]
constexpr size_t OFF_T     = OFF_RT + 262144;
constexpr size_t OFF_NORMP = OFF_T + 262144;       // 4*16*256 = 16384
// ends at OFF_NORMP + 16384 = 1,196,032 floats (~4.8 MB)

// ---- K1: w = x(256x128) @ Ww(128x512), 32x32 tile, prefetch dbuf ----
//      also initializes out = bias (broadcast) for the atomic projection.
__global__ __launch_bounds__(256) void k_w(const float* __restrict__ x,
                                           const float* __restrict__ Ww,
                                           float* __restrict__ w,
                                           const float* __restrict__ bp,
                                           float* __restrict__ out) {
    __shared__ __align__(16) float As[1152];  // [k][i]
    __shared__ __align__(16) float Bs[1152];  // [k][j]
    int j0 = blockIdx.x * 32, i0 = blockIdx.y * 32;
    int t = threadIdx.x, tx = t & 15, ty = t >> 4, r = t >> 3, g = t & 7;
    {   // bias-init out: 128 blocks * 256 threads == 32768 == out elements
        int oidx = (blockIdx.y * 16 + blockIdx.x) * 256 + t;
        out[oidx] = bp[oidx & 127];
    }
    float4 a4 = *(const float4*)&x[(size_t)(i0 + r) * 128 + g * 4];
    float4 b4 = *(const float4*)&Ww[(size_t)r * 512 + j0 + g * 4];
    float a00 = 0, a01 = 0, a10 = 0, a11 = 0;
    for (int kc = 0; kc < 128; kc += 32) {
        As[(g * 4 + 0) * 36 + r] = a4.x; As[(g * 4 + 1) * 36 + r] = a4.y;
        As[(g * 4 + 2) * 36 + r] = a4.z; As[(g * 4 + 3) * 36 + r] = a4.w;
        *(float4*)&Bs[r * 36 + g * 4] = b4;
        __syncthreads();
        if (kc + 32 < 128) {
            a4 = *(const float4*)&x[(size_t)(i0 + r) * 128 + kc + 32 + g * 4];
            b4 = *(const float4*)&Ww[(size_t)(kc + 32 + r) * 512 + j0 + g * 4];
        }
#pragma unroll
        for (int kk = 0; kk < 32; kk++) {
            float2 av = *(float2*)&As[kk * 36 + ty * 2];
            float2 bv = *(float2*)&Bs[kk * 36 + tx * 2];
            a00 += av.x * bv.x; a01 += av.x * bv.y;
            a10 += av.y * bv.x; a11 += av.y * bv.y;
        }
        __syncthreads();
    }
    *(float2*)&w[(size_t)(i0 + ty * 2) * 512 + j0 + tx * 2] = make_float2(a00, a01);
    *(float2*)&w[(size_t)(i0 + ty * 2 + 1) * 512 + j0 + tx * 2] = make_float2(a10, a11);
}

// ---- K2: fused PQR + T + normp. grid (8, 16, 4) = 512 blocks. ----
// Tile: i0..i0+15 (rows), k0..k0+31 (cols). 2 blocks/CU.
__global__ __launch_bounds__(256, 2) void k_T(const float* __restrict__ w,
                                              float* __restrict__ P,
                                              float* __restrict__ Q,
                                              float* __restrict__ Rt,
                                              float* __restrict__ T,
                                              float* __restrict__ normp) {
    __shared__ __align__(16) float aT[640];   // [d32][i16] stride 20
    __shared__ __align__(16) float cT[1152];  // [d32][k32] stride 36
    __shared__ __align__(16) float bT[1152];  // [d32][j32] stride 36
    __shared__ __align__(16) float Ps[640];   // [j32][i16] stride 20
    __shared__ __align__(16) float Rs[1152];  // [j32][k32] stride 36
    int h = blockIdx.z, k0 = blockIdx.x * 32, i0 = blockIdx.y * 16;
    size_t hb = (size_t)h * 65536;
    int t = threadIdx.x, tx = t & 15, ty = t >> 4, r = t >> 3, g = t & 7;
    const float sc = 0.17677669529663687f;

    if (t < 128) {  // stage aT: 16 rows x 32 d
        int row = t >> 3, c4 = (t & 7) * 4;
        float4 a4 = *(const float4*)&w[(size_t)(i0 + row) * 512 + h * 32 + c4];
        aT[(c4 + 0) * 20 + row] = a4.x; aT[(c4 + 1) * 20 + row] = a4.y;
        aT[(c4 + 2) * 20 + row] = a4.z; aT[(c4 + 3) * 20 + row] = a4.w;
    }
    {   // stage cT: 32 rows (k) x 32 d
        float4 c4v = *(const float4*)&w[(size_t)(k0 + r) * 512 + 256 + h * 32 + g * 4];
        cT[(g * 4 + 0) * 36 + r] = c4v.x; cT[(g * 4 + 1) * 36 + r] = c4v.y;
        cT[(g * 4 + 2) * 36 + r] = c4v.z; cT[(g * 4 + 3) * 36 + r] = c4v.w;
    }
    float4 bv = *(const float4*)&w[(size_t)r * 512 + 128 + h * 32 + g * 4];  // j-chunk 0
    __syncthreads();

    // Q tile: i = ty, k = 2tx+{0,1}
    float dq0 = 0, dq1 = 0;
#pragma unroll
    for (int d = 0; d < 32; d++) {
        float av = aT[d * 20 + ty];
        float2 c2 = *(float2*)&cT[d * 36 + 2 * tx];
        dq0 += av * c2.x; dq1 += av * c2.y;
    }
    float q0 = __expf(sc * dq0), q1 = __expf(sc * dq1);
    *(float2*)&Q[hb + (size_t)(i0 + ty) * 256 + k0 + 2 * tx] = make_float2(q0, q1);

    const bool wP = (k0 == 0), wR = (blockIdx.y == 0);
    float acc0 = 0, acc1 = 0;  // T[i=ty][k=2tx+{0,1}]
    for (int jc = 0; jc < 256; jc += 32) {
        bT[(g * 4 + 0) * 36 + r] = bv.x; bT[(g * 4 + 1) * 36 + r] = bv.y;
        bT[(g * 4 + 2) * 36 + r] = bv.z; bT[(g * 4 + 3) * 36 + r] = bv.w;
        __syncthreads();  // A: bT ready
        if (jc + 32 < 256)
            bv = *(const float4*)&w[(size_t)(jc + 32 + r) * 512 + 128 + h * 32 + g * 4];
        // P chunk: j = 2ty+{0,1}, i = tx ; R chunk: j = 2ty+{0,1}, k = 2tx+{0,1}
        float dp0 = 0, dp1 = 0, dr00 = 0, dr01 = 0, dr10 = 0, dr11 = 0;
#pragma unroll
        for (int d = 0; d < 32; d++) {
            float2 b2 = *(float2*)&bT[d * 36 + 2 * ty];
            float av = aT[d * 20 + tx];
            float2 c2 = *(float2*)&cT[d * 36 + 2 * tx];
            dp0 += b2.x * av; dp1 += b2.y * av;
            dr00 += b2.x * c2.x; dr01 += b2.x * c2.y;
            dr10 += b2.y * c2.x; dr11 += b2.y * c2.y;
        }
        float p0 = __expf(sc * dp0), p1 = __expf(sc * dp1);
        float r00 = __expf(sc * dr00), r01 = __expf(sc * dr01);
        float r10 = __expf(sc * dr10), r11 = __expf(sc * dr11);
        Ps[(2 * ty + 0) * 20 + tx] = p0;
        Ps[(2 * ty + 1) * 20 + tx] = p1;
        *(float2*)&Rs[(2 * ty + 0) * 36 + 2 * tx] = make_float2(r00, r01);
        *(float2*)&Rs[(2 * ty + 1) * 36 + 2 * tx] = make_float2(r10, r11);
        if (wP)  // P[i][j]: i = i0+tx, j-pair = jc+2ty
            *(float2*)&P[hb + (size_t)(i0 + tx) * 256 + jc + 2 * ty] = make_float2(p0, p1);
        if (wR) {  // Rt[k][j]: k = k0+2tx+kk, j-pair = jc+2ty
            *(float2*)&Rt[hb + (size_t)(k0 + 2 * tx + 0) * 256 + jc + 2 * ty] = make_float2(r00, r10);
            *(float2*)&Rt[hb + (size_t)(k0 + 2 * tx + 1) * 256 + jc + 2 * ty] = make_float2(r01, r11);
        }
        __syncthreads();  // B: Ps/Rs ready
#pragma unroll
        for (int j = 0; j < 32; j++) {
            float pv = Ps[j * 20 + ty];
            float2 r2 = *(float2*)&Rs[j * 36 + 2 * tx];
            acc0 += pv * r2.x; acc1 += pv * r2.y;
        }
    }
    *(float2*)&T[hb + (size_t)(i0 + ty) * 256 + k0 + 2 * tx] = make_float2(acc0, acc1);
    __syncthreads();
    float* red = Ps;  // [16][34] needs 544 <= 640
    red[ty * 34 + 2 * tx]     = q0 * acc0;
    red[ty * 34 + 2 * tx + 1] = q1 * acc1;
    __syncthreads();
    if (t < 32) {
        float s = 0.f;
#pragma unroll
        for (int m = 0; m < 16; m++) s += red[m * 34 + t];
        normp[h * 4096 + blockIdx.y * 256 + k0 + t] = s;
    }
}

// ---- K3: S rows + x1x2 + projection. grid (64, 4) = 256 blocks, 4 rows each. ----
__global__ __launch_bounds__(256) void k_x1x2S(
    const float* __restrict__ P, const float* __restrict__ Q,
    const float* __restrict__ Rt, const float* __restrict__ T,
    const float* __restrict__ normp, const float* __restrict__ w,
    const float* __restrict__ Wp, float* __restrict__ out) {
    int h = blockIdx.y;
    int i0 = blockIdx.x * 4;
    size_t hb = (size_t)h * 65536;
    __shared__ float rn_s[256];                 // later reused as ys[4][33]
    __shared__ __align__(16) float qs[1024];    // Q*rn rows [4][256]; later redx/redy
    __shared__ __align__(16) float wp[1024];    // [4][256]
    __shared__ __align__(16) float wq[1024];    // [4][256]
    __shared__ __align__(16) float big[8192];   // Rts[32][256] / vls[256][32] / Wps[32][128]
    int t = threadIdx.x;
    {
        float s = 0.f;
#pragma unroll
        for (int ib = 0; ib < 16; ib++) s += normp[h * 4096 + ib * 256 + t];
        rn_s[t] = 1.f / fmaxf(s, 1e-6f);
    }
    __syncthreads();
    int row = t >> 6, jq = (t & 63) * 4;
    {   // qs = Q rows * rn
        float4 q4 = *(const float4*)&Q[hb + (size_t)(i0 + row) * 256 + jq];
        q4.x *= rn_s[jq + 0]; q4.y *= rn_s[jq + 1];
        q4.z *= rn_s[jq + 2]; q4.w *= rn_s[jq + 3];
        *(float4*)&qs[row * 256 + jq] = q4;
    }
    // S rows: s4[j..j+3] of row `row` = sum_k qs[row][k] * Rt[k][j..j+3]
    float4 s4 = {0.f, 0.f, 0.f, 0.f};
    for (int kc = 0; kc < 256; kc += 32) {
#pragma unroll
        for (int m = 0; m < 8; m++) {  // stage Rts chunk [32][256]
            int rr = 4 * m + (t >> 6), cc = (t & 63) * 4;
            *(float4*)&big[rr * 256 + cc] =
                *(const float4*)&Rt[hb + (size_t)(kc + rr) * 256 + cc];
        }
        __syncthreads();
#pragma unroll
        for (int kk = 0; kk < 32; kk++) {
            float qv = qs[row * 256 + kc + kk];
            float4 r4 = *(float4*)&big[kk * 256 + jq];
            s4.x += qv * r4.x; s4.y += qv * r4.y;
            s4.z += qv * r4.z; s4.w += qv * r4.w;
        }
        __syncthreads();
    }
    {   // wp = P .* S ; wq = (Q rn) .* T
        float4 p4 = *(const float4*)&P[hb + (size_t)(i0 + row) * 256 + jq];
        float4 t4 = *(const float4*)&T[hb + (size_t)(i0 + row) * 256 + jq];
        float4 q4 = *(float4*)&qs[row * 256 + jq];
        float4 wpv, wqv;
        wpv.x = p4.x * s4.x; wpv.y = p4.y * s4.y;
        wpv.z = p4.z * s4.z; wpv.w = p4.w * s4.w;
        wqv.x = q4.x * t4.x; wqv.y = q4.y * t4.y;
        wqv.z = q4.z * t4.z; wqv.w = q4.w * t4.w;
        *(float4*)&wp[row * 256 + jq] = wpv;
        *(float4*)&wq[row * 256 + jq] = wqv;
    }
#pragma unroll
    for (int m = 0; m < 8; m++) {  // stage vls [256][32] into big
        int jj = 32 * m + (t >> 3), dd = (t & 7) * 4;
        *(float4*)&big[jj * 32 + dd] =
            *(const float4*)&w[(size_t)jj * 512 + 384 + h * 32 + dd];
    }
    __syncthreads();  // wp/wq/vls ready
    // contraction: thread (d = t&31, row2 = (t>>5)&3, jh = t>>7) does half the j range
    int d = t & 31, row2 = (t >> 5) & 3, jh = t >> 7;
    float x1 = 0.f, x2 = 0.f;
    {
        int jbase = jh * 128;
#pragma unroll 8
        for (int j = 0; j < 128; j++) {
            float vv = big[(jbase + j) * 32 + d];
            x1 += wp[row2 * 256 + jbase + j] * vv;
            x2 += wq[row2 * 256 + jbase + j] * vv;
        }
    }
    float* redx = qs;        // reuse
    float* redy = qs + 512;
    redx[t] = x1;
    redy[t] = x2;
    __syncthreads();
    float* ys = rn_s;  // [4][33]
    if (t < 128) {
        float x1t = redx[t] + redx[t + 128];
        float x2t = redy[t] + redy[t + 128];
        ys[row2 * 33 + d] = x1t * x2t;
    }
#pragma unroll
    for (int m = 0; m < 4; m++) {  // stage Wps [32][128] into big
        int k = 8 * m + (t >> 5), n = (t & 31) * 4;
        *(float4*)&big[k * 128 + n] =
            *(const float4*)&Wp[(size_t)(h * 32 + k) * 128 + n];
    }
    __syncthreads();  // ys + Wps ready
    int n = t & 127, ti = t >> 7;  // rows ti, ti+2
    float acc0 = 0.f, acc1 = 0.f;
#pragma unroll
    for (int k = 0; k < 32; k++) {
        float wv = big[k * 128 + n];
        acc0 += ys[(ti + 0) * 33 + k] * wv;
        acc1 += ys[(ti + 2) * 33 + k] * wv;
    }
    atomicAdd(&out[(size_t)(i0 + ti + 0) * 128 + n], acc0);
    atomicAdd(&out[(size_t)(i0 + ti + 2) * 128 + n], acc1);
}

extern "C" void kernel_launch(void* const* d_in, const int* in_sizes, int n_in,
                              void* d_out, int out_size, void* d_ws, size_t ws_size,
                              hipStream_t stream) {
    const float* x      = (const float*)d_in[0];
    const float* W_w    = (const float*)d_in[1];
    const float* W_proj = (const float*)d_in[2];
    const float* b_proj = (const float*)d_in[3];
    float* out = (float*)d_out;
    float* ws  = (float*)d_ws;

    float* w     = ws + OFF_W;
    float* P     = ws + OFF_P;
    float* Q     = ws + OFF_Q;
    float* Rt    = ws + OFF_RT;
    float* T     = ws + OFF_T;
    float* normp = ws + OFF_NORMP;

    k_w<<<dim3(16, 8), 256, 0, stream>>>(x, W_w, w, b_proj, out);
    k_T<<<dim3(8, 16, 4), 256, 0, stream>>>(w, P, Q, Rt, T, normp);
    k_x1x2S<<<dim3(64, 4), 256, 0, stream>>>(P, Q, Rt, T, normp, w, W_proj, out);
}

// Round 8
// 41.574 us; speedup vs baseline: 1.3294x; 1.3294x over previous
//
#include <hip/hip_runtime.h>
#include <hip/hip_bf16.h>

// B=1, NN=256, C=128, H=4, D=32 — O(N^3) factorization, 4 kernels.
//   k_w:  w = x @ W_w (256x512); also out = bias (for later atomics)
//   k_T:  P,Q,R on the fly; T = P R split along j into 2 halves (T0,T1);
//         Q,P,Rt side-writes; normp partials (linear in T). 512 blocks.
//   k_S:  S = (Q rn) @ Rt split along k into 2 halves (S0,S1). 512 blocks.
//   k_x1x2: wp = P.*(S0+S1), wq = Q.*rn.*(T0+T1); x1 = wp v, x2 = wq v;
//         y = x1.*x2; out += y @ W_proj[h-slice] (atomicAdd, bias-init by k_w).

constexpr size_t OFF_W     = 0;                     // 256*512
constexpr size_t OFF_P     = 131072;                // 4*65536
constexpr size_t OFF_Q     = OFF_P + 262144;
constexpr size_t OFF_RT    = OFF_Q + 262144;        // R^T: [h][k][j]
constexpr size_t OFF_T     = OFF_RT + 262144;       // two j-halves: 2*262144
constexpr size_t OFF_S     = OFF_T + 524288;        // two k-halves: 2*262144
constexpr size_t OFF_NORMP = OFF_S + 524288;        // 4*16*256 = 16384
// ends at 1,982,464 floats (~7.9 MB); ws is ~268 MB per poison-fill counters.

// ---- K1: w = x(256x128) @ Ww(128x512), 32x32 tile, prefetch dbuf ----
//      also initializes out = bias (broadcast) for the atomic projection.
__global__ __launch_bounds__(256) void k_w(const float* __restrict__ x,
                                           const float* __restrict__ Ww,
                                           float* __restrict__ w,
                                           const float* __restrict__ bp,
                                           float* __restrict__ out) {
    __shared__ __align__(16) float As[1152];  // [k][i]
    __shared__ __align__(16) float Bs[1152];  // [k][j]
    int j0 = blockIdx.x * 32, i0 = blockIdx.y * 32;
    int t = threadIdx.x, tx = t & 15, ty = t >> 4, r = t >> 3, g = t & 7;
    {   // bias-init out: 128 blocks * 256 threads == 32768 == out elements
        int oidx = (blockIdx.y * 16 + blockIdx.x) * 256 + t;
        out[oidx] = bp[oidx & 127];
    }
    float4 a4 = *(const float4*)&x[(size_t)(i0 + r) * 128 + g * 4];
    float4 b4 = *(const float4*)&Ww[(size_t)r * 512 + j0 + g * 4];
    float a00 = 0, a01 = 0, a10 = 0, a11 = 0;
    for (int kc = 0; kc < 128; kc += 32) {
        As[(g * 4 + 0) * 36 + r] = a4.x; As[(g * 4 + 1) * 36 + r] = a4.y;
        As[(g * 4 + 2) * 36 + r] = a4.z; As[(g * 4 + 3) * 36 + r] = a4.w;
        *(float4*)&Bs[r * 36 + g * 4] = b4;
        __syncthreads();
        if (kc + 32 < 128) {
            a4 = *(const float4*)&x[(size_t)(i0 + r) * 128 + kc + 32 + g * 4];
            b4 = *(const float4*)&Ww[(size_t)(kc + 32 + r) * 512 + j0 + g * 4];
        }
#pragma unroll
        for (int kk = 0; kk < 32; kk++) {
            float2 av = *(float2*)&As[kk * 36 + ty * 2];
            float2 bv = *(float2*)&Bs[kk * 36 + tx * 2];
            a00 += av.x * bv.x; a01 += av.x * bv.y;
            a10 += av.y * bv.x; a11 += av.y * bv.y;
        }
        __syncthreads();
    }
    *(float2*)&w[(size_t)(i0 + ty * 2) * 512 + j0 + tx * 2] = make_float2(a00, a01);
    *(float2*)&w[(size_t)(i0 + ty * 2 + 1) * 512 + j0 + tx * 2] = make_float2(a10, a11);
}

// ---- K2: fused PQR + T(j-half) + normp. grid (8, 8, 8): z = h*2+jh. ----
__global__ __launch_bounds__(256, 2) void k_T(const float* __restrict__ w,
                                              float* __restrict__ P,
                                              float* __restrict__ Q,
                                              float* __restrict__ Rt,
                                              float* __restrict__ T,
                                              float* __restrict__ normp) {
    __shared__ __align__(16) float aT[1152];  // [d][i]
    __shared__ __align__(16) float cT[1152];  // [d][k]
    __shared__ __align__(16) float bT[1152];  // [d][j]
    __shared__ __align__(16) float Ps[1152];  // [j][i]
    __shared__ __align__(16) float Rs[1152];  // [j][k]
    int h = blockIdx.z >> 1, jh = blockIdx.z & 1;
    int k0 = blockIdx.x * 32, i0 = blockIdx.y * 32;
    int jc0 = jh * 128;
    size_t hb = (size_t)h * 65536;
    int t = threadIdx.x, tx = t & 15, ty = t >> 4, r = t >> 3, g = t & 7;
    const float sc = 0.17677669529663687f;

    float4 av = *(const float4*)&w[(size_t)(i0 + r) * 512 + h * 32 + g * 4];
    aT[(g * 4 + 0) * 36 + r] = av.x; aT[(g * 4 + 1) * 36 + r] = av.y;
    aT[(g * 4 + 2) * 36 + r] = av.z; aT[(g * 4 + 3) * 36 + r] = av.w;
    float4 cv = *(const float4*)&w[(size_t)(k0 + r) * 512 + 256 + h * 32 + g * 4];
    cT[(g * 4 + 0) * 36 + r] = cv.x; cT[(g * 4 + 1) * 36 + r] = cv.y;
    cT[(g * 4 + 2) * 36 + r] = cv.z; cT[(g * 4 + 3) * 36 + r] = cv.w;
    // prefetch first b chunk of this j-half
    float4 bv = *(const float4*)&w[(size_t)(jc0 + r) * 512 + 128 + h * 32 + g * 4];
    __syncthreads();

    // Q tile: i = 2ty+ii, k = 2tx+kk (computed by both jh for normp; written once)
    float dq00 = 0, dq01 = 0, dq10 = 0, dq11 = 0;
#pragma unroll
    for (int d = 0; d < 32; d++) {
        float2 a2 = *(float2*)&aT[d * 36 + ty * 2];
        float2 c2 = *(float2*)&cT[d * 36 + tx * 2];
        dq00 += a2.x * c2.x; dq01 += a2.x * c2.y;
        dq10 += a2.y * c2.x; dq11 += a2.y * c2.y;
    }
    float q00 = __expf(sc * dq00), q01 = __expf(sc * dq01);
    float q10 = __expf(sc * dq10), q11 = __expf(sc * dq11);
    if (jh == 0) {
        *(float2*)&Q[hb + (size_t)(i0 + ty * 2) * 256 + k0 + tx * 2] = make_float2(q00, q01);
        *(float2*)&Q[hb + (size_t)(i0 + ty * 2 + 1) * 256 + k0 + tx * 2] = make_float2(q10, q11);
    }

    const bool wP = (k0 == 0), wR = (blockIdx.y == 0);
    float acc00 = 0, acc01 = 0, acc10 = 0, acc11 = 0;
    for (int jc = jc0; jc < jc0 + 128; jc += 32) {
        bT[(g * 4 + 0) * 36 + r] = bv.x; bT[(g * 4 + 1) * 36 + r] = bv.y;
        bT[(g * 4 + 2) * 36 + r] = bv.z; bT[(g * 4 + 3) * 36 + r] = bv.w;
        __syncthreads();  // A: bT ready, prior Ps/Rs reads done
        if (jc + 32 < jc0 + 128)
            bv = *(const float4*)&w[(size_t)(jc + 32 + r) * 512 + 128 + h * 32 + g * 4];
        float dp00 = 0, dp01 = 0, dp10 = 0, dp11 = 0;
        float dr00 = 0, dr01 = 0, dr10 = 0, dr11 = 0;
#pragma unroll
        for (int d = 0; d < 32; d++) {
            float2 b2 = *(float2*)&bT[d * 36 + ty * 2];
            float2 a2 = *(float2*)&aT[d * 36 + tx * 2];
            float2 c2 = *(float2*)&cT[d * 36 + tx * 2];
            dp00 += b2.x * a2.x; dp01 += b2.x * a2.y;
            dp10 += b2.y * a2.x; dp11 += b2.y * a2.y;
            dr00 += b2.x * c2.x; dr01 += b2.x * c2.y;
            dr10 += b2.y * c2.x; dr11 += b2.y * c2.y;
        }
        float p00 = __expf(sc * dp00), p01 = __expf(sc * dp01);
        float p10 = __expf(sc * dp10), p11 = __expf(sc * dp11);
        float r00 = __expf(sc * dr00), r01 = __expf(sc * dr01);
        float r10 = __expf(sc * dr10), r11 = __expf(sc * dr11);
        *(float2*)&Ps[(ty * 2 + 0) * 36 + tx * 2] = make_float2(p00, p01);
        *(float2*)&Ps[(ty * 2 + 1) * 36 + tx * 2] = make_float2(p10, p11);
        *(float2*)&Rs[(ty * 2 + 0) * 36 + tx * 2] = make_float2(r00, r01);
        *(float2*)&Rs[(ty * 2 + 1) * 36 + tx * 2] = make_float2(r10, r11);
        if (wP) {  // P[i][j], i = i0+2tx+ii, j-pair = jc+2ty (this jh's range)
            *(float2*)&P[hb + (size_t)(i0 + tx * 2 + 0) * 256 + jc + ty * 2] = make_float2(p00, p10);
            *(float2*)&P[hb + (size_t)(i0 + tx * 2 + 1) * 256 + jc + ty * 2] = make_float2(p01, p11);
        }
        if (wR) {  // Rt[k][j], k = k0+2tx+kk, j-pair = jc+2ty
            *(float2*)&Rt[hb + (size_t)(k0 + tx * 2 + 0) * 256 + jc + ty * 2] = make_float2(r00, r10);
            *(float2*)&Rt[hb + (size_t)(k0 + tx * 2 + 1) * 256 + jc + ty * 2] = make_float2(r01, r11);
        }
        __syncthreads();  // B: Ps/Rs ready
#pragma unroll
        for (int j = 0; j < 32; j++) {
            float2 p2 = *(float2*)&Ps[j * 36 + ty * 2];
            float2 r2 = *(float2*)&Rs[j * 36 + tx * 2];
            acc00 += p2.x * r2.x; acc01 += p2.x * r2.y;
            acc10 += p2.y * r2.x; acc11 += p2.y * r2.y;
        }
    }
    float* Tp = T + (size_t)jh * 262144;
    *(float2*)&Tp[hb + (size_t)(i0 + ty * 2) * 256 + k0 + tx * 2] = make_float2(acc00, acc01);
    *(float2*)&Tp[hb + (size_t)(i0 + ty * 2 + 1) * 256 + k0 + tx * 2] = make_float2(acc10, acc11);
    __syncthreads();
    float* red = Ps;  // [16][34]
    red[ty * 34 + tx * 2]     = q00 * acc00 + q10 * acc10;
    red[ty * 34 + tx * 2 + 1] = q01 * acc01 + q11 * acc11;
    __syncthreads();
    if (t < 32) {
        float s = 0.f;
#pragma unroll
        for (int m = 0; m < 16; m++) s += red[m * 34 + t];
        normp[h * 4096 + (jh * 8 + blockIdx.y) * 256 + k0 + t] = s;
    }
}

// ---- K3: S(k-half) = (Q rn) @ Rt. grid (8, 8, 8): z = h*2+kh. ----
__global__ __launch_bounds__(256, 2) void k_S(const float* __restrict__ Q,
                                              const float* __restrict__ Rt,
                                              const float* __restrict__ normp,
                                              float* __restrict__ S) {
    __shared__ __align__(16) float As[1152];  // [k][i] (Q*rn transposed)
    __shared__ __align__(16) float Bs[1152];  // [k][j] (Rt natural)
    __shared__ float rn_s[256];
    int h = blockIdx.z >> 1, kh = blockIdx.z & 1;
    int j0 = blockIdx.x * 32, i0 = blockIdx.y * 32;
    int kc0 = kh * 128;
    size_t hb = (size_t)h * 65536;
    int t = threadIdx.x, tx = t & 15, ty = t >> 4, r = t >> 3, g = t & 7;
    {
        float s = 0.f;
#pragma unroll
        for (int ib = 0; ib < 16; ib++) s += normp[h * 4096 + ib * 256 + t];
        rn_s[t] = 1.f / fmaxf(s, 1e-6f);
    }
    float4 a4 = *(const float4*)&Q[hb + (size_t)(i0 + r) * 256 + kc0 + g * 4];
    float4 b4 = *(const float4*)&Rt[hb + (size_t)(kc0 + r) * 256 + j0 + g * 4];
    __syncthreads();  // rn_s ready
    float a00 = 0, a01 = 0, a10 = 0, a11 = 0;
    for (int kc = kc0; kc < kc0 + 128; kc += 32) {
        As[(g * 4 + 0) * 36 + r] = a4.x * rn_s[kc + g * 4 + 0];
        As[(g * 4 + 1) * 36 + r] = a4.y * rn_s[kc + g * 4 + 1];
        As[(g * 4 + 2) * 36 + r] = a4.z * rn_s[kc + g * 4 + 2];
        As[(g * 4 + 3) * 36 + r] = a4.w * rn_s[kc + g * 4 + 3];
        *(float4*)&Bs[r * 36 + g * 4] = b4;
        __syncthreads();
        if (kc + 32 < kc0 + 128) {
            a4 = *(const float4*)&Q[hb + (size_t)(i0 + r) * 256 + kc + 32 + g * 4];
            b4 = *(const float4*)&Rt[hb + (size_t)(kc + 32 + r) * 256 + j0 + g * 4];
        }
#pragma unroll
        for (int kk = 0; kk < 32; kk++) {
            float2 av = *(float2*)&As[kk * 36 + ty * 2];
            float2 bv = *(float2*)&Bs[kk * 36 + tx * 2];
            a00 += av.x * bv.x; a01 += av.x * bv.y;
            a10 += av.y * bv.x; a11 += av.y * bv.y;
        }
        __syncthreads();
    }
    float* Sp = S + (size_t)kh * 262144;
    *(float2*)&Sp[hb + (size_t)(i0 + ty * 2) * 256 + j0 + tx * 2] = make_float2(a00, a01);
    *(float2*)&Sp[hb + (size_t)(i0 + ty * 2 + 1) * 256 + j0 + tx * 2] = make_float2(a10, a11);
}

// ---- K4: x1,x2,y + fused partial projection (atomicAdd into out). ----
// grid (32, 4): block = (8 rows, head h). out must be bias-initialized (k_w).
__global__ __launch_bounds__(256) void k_x1x2(
    const float* __restrict__ P, const float* __restrict__ Q,
    const float* __restrict__ S, const float* __restrict__ T,
    const float* __restrict__ normp, const float* __restrict__ w,
    const float* __restrict__ Wp, float* __restrict__ out) {
    int h = blockIdx.y;
    int i0 = blockIdx.x * 8;
    size_t hb = (size_t)h * 65536;
    __shared__ __align__(16) float wp[2048];    // [8][256]
    __shared__ __align__(16) float wq[2048];
    __shared__ __align__(16) float vls[8192];   // [256][32]
    __shared__ float rn_s[256];
    int t = threadIdx.x;
    {
        float s = 0.f;
#pragma unroll
        for (int ib = 0; ib < 16; ib++) s += normp[h * 4096 + ib * 256 + t];
        rn_s[t] = 1.f / fmaxf(s, 1e-6f);
    }
    __syncthreads();
#pragma unroll
    for (int m = 0; m < 2; m++) {
        int lin = (m * 256 + t) * 4;
        int rr = lin >> 8, jj = lin & 255;
        size_t o = hb + (size_t)(i0 + rr) * 256 + jj;
        float4 p4 = *(const float4*)&P[o];
        float4 s4a = *(const float4*)&S[o];
        float4 s4b = *(const float4*)&S[o + 262144];
        float4 q4 = *(const float4*)&Q[o];
        float4 t4a = *(const float4*)&T[o];
        float4 t4b = *(const float4*)&T[o + 262144];
        float4 wpv, wqv;
        wpv.x = p4.x * (s4a.x + s4b.x); wpv.y = p4.y * (s4a.y + s4b.y);
        wpv.z = p4.z * (s4a.z + s4b.z); wpv.w = p4.w * (s4a.w + s4b.w);
        wqv.x = q4.x * (t4a.x + t4b.x) * rn_s[jj + 0];
        wqv.y = q4.y * (t4a.y + t4b.y) * rn_s[jj + 1];
        wqv.z = q4.z * (t4a.z + t4b.z) * rn_s[jj + 2];
        wqv.w = q4.w * (t4a.w + t4b.w) * rn_s[jj + 3];
        *(float4*)&wp[rr * 256 + jj] = wpv;
        *(float4*)&wq[rr * 256 + jj] = wqv;
    }
#pragma unroll
    for (int m = 0; m < 8; m++) {
        int lin = (m * 256 + t) * 4;
        int jj = lin >> 5, dd = lin & 31;
        *(float4*)&vls[jj * 32 + dd] =
            *(const float4*)&w[(size_t)jj * 512 + 384 + h * 32 + dd];
    }
    __syncthreads();
    int d = t & 31, rl = t >> 5;
    float x1 = 0.f, x2 = 0.f;
#pragma unroll 8
    for (int j = 0; j < 256; j++) {
        float vv = vls[j * 32 + d];
        x1 += wp[rl * 256 + j] * vv;
        x2 += wq[rl * 256 + j] * vv;
    }
    float yv = x1 * x2;  // y[i0+rl][h*32+d]
    __syncthreads();     // done reading wp/vls; reuse as ys / Wps
    float* ys = wp;      // [8][33]
    float* Wps = vls;    // [32][128]
    ys[rl * 33 + d] = yv;
#pragma unroll
    for (int m = 0; m < 4; m++) {
        int idx = m * 256 + t;        // float4 index, 1024 total
        int lin = idx * 4;
        int k = lin >> 7, n = lin & 127;
        *(float4*)&Wps[k * 128 + n] =
            *(const float4*)&Wp[(size_t)(h * 32 + k) * 128 + n];
    }
    __syncthreads();
    int n = t & 127, ti = t >> 7;     // ti in {0,1}; rows ti, ti+2, ti+4, ti+6
    float acc0 = 0, acc1 = 0, acc2 = 0, acc3 = 0;
#pragma unroll
    for (int k = 0; k < 32; k++) {
        float wv = Wps[k * 128 + n];
        acc0 += ys[(ti + 0) * 33 + k] * wv;
        acc1 += ys[(ti + 2) * 33 + k] * wv;
        acc2 += ys[(ti + 4) * 33 + k] * wv;
        acc3 += ys[(ti + 6) * 33 + k] * wv;
    }
    atomicAdd(&out[(size_t)(i0 + ti + 0) * 128 + n], acc0);
    atomicAdd(&out[(size_t)(i0 + ti + 2) * 128 + n], acc1);
    atomicAdd(&out[(size_t)(i0 + ti + 4) * 128 + n], acc2);
    atomicAdd(&out[(size_t)(i0 + ti + 6) * 128 + n], acc3);
}

extern "C" void kernel_launch(void* const* d_in, const int* in_sizes, int n_in,
                              void* d_out, int out_size, void* d_ws, size_t ws_size,
                              hipStream_t stream) {
    const float* x      = (const float*)d_in[0];
    const float* W_w    = (const float*)d_in[1];
    const float* W_proj = (const float*)d_in[2];
    const float* b_proj = (const float*)d_in[3];
    float* out = (float*)d_out;
    float* ws  = (float*)d_ws;

    float* w     = ws + OFF_W;
    float* P     = ws + OFF_P;
    float* Q     = ws + OFF_Q;
    float* Rt    = ws + OFF_RT;
    float* T     = ws + OFF_T;
    float* S     = ws + OFF_S;
    float* normp = ws + OFF_NORMP;

    k_w<<<dim3(16, 8), 256, 0, stream>>>(x, W_w, w, b_proj, out);
    k_T<<<dim3(8, 8, 8), 256, 0, stream>>>(w, P, Q, Rt, T, normp);
    k_S<<<dim3(8, 8, 8), 256, 0, stream>>>(Q, Rt, normp, S);
    k_x1x2<<<dim3(32, 4), 256, 0, stream>>>(P, Q, S, T, normp, w, W_proj, out);
}

// Round 9
// 39.769 us; speedup vs baseline: 1.3897x; 1.0454x over previous
//
#include <hip/hip_runtime.h>
#include <hip/hip_bf16.h>

// B=1, NN=256, C=128, H=4, D=32 — O(N^3) factorization, 4 kernels.
//   k_w:  w = x @ W_w (256x512); also out = bias (for later atomics)
//   k_T:  P,Q,R on the fly; T = P R split along j into 2 halves (T0,T1);
//         Q,P,Rt side-writes; normp partials. reg-cached a/c fragments,
//         float4 T-accum via transposed Ps/Rs. 512 blocks, 2/CU.
//   k_S:  S = (Q rn) @ Rt split along k into 2 halves (S0,S1); float4 dots.
//   k_x1x2: wp = P.*(S0+S1), wq = Q.*rn.*(T0+T1); x1 = wp v, x2 = wq v via
//         transposed vT + float4 reads; y = x1.*x2; out += y @ W_proj[h]
//         (atomicAdd, bias-init by k_w). grid (64,4) = 256 blocks.

constexpr size_t OFF_W     = 0;                     // 256*512
constexpr size_t OFF_P     = 131072;                // 4*65536
constexpr size_t OFF_Q     = OFF_P + 262144;
constexpr size_t OFF_RT    = OFF_Q + 262144;        // R^T: [h][k][j]
constexpr size_t OFF_T     = OFF_RT + 262144;       // two j-halves: 2*262144
constexpr size_t OFF_S     = OFF_T + 524288;        // two k-halves: 2*262144
constexpr size_t OFF_NORMP = OFF_S + 524288;        // 4*16*256 = 16384

// ---- K1: w = x(256x128) @ Ww(128x512), 32x32 tile, prefetch dbuf ----
__global__ __launch_bounds__(256) void k_w(const float* __restrict__ x,
                                           const float* __restrict__ Ww,
                                           float* __restrict__ w,
                                           const float* __restrict__ bp,
                                           float* __restrict__ out) {
    __shared__ __align__(16) float As[1152];  // [k][i]
    __shared__ __align__(16) float Bs[1152];  // [k][j]
    int j0 = blockIdx.x * 32, i0 = blockIdx.y * 32;
    int t = threadIdx.x, tx = t & 15, ty = t >> 4, r = t >> 3, g = t & 7;
    {   // bias-init out: 128 blocks * 256 threads == 32768 == out elements
        int oidx = (blockIdx.y * 16 + blockIdx.x) * 256 + t;
        out[oidx] = bp[oidx & 127];
    }
    float4 a4 = *(const float4*)&x[(size_t)(i0 + r) * 128 + g * 4];
    float4 b4 = *(const float4*)&Ww[(size_t)r * 512 + j0 + g * 4];
    float a00 = 0, a01 = 0, a10 = 0, a11 = 0;
    for (int kc = 0; kc < 128; kc += 32) {
        As[(g * 4 + 0) * 36 + r] = a4.x; As[(g * 4 + 1) * 36 + r] = a4.y;
        As[(g * 4 + 2) * 36 + r] = a4.z; As[(g * 4 + 3) * 36 + r] = a4.w;
        *(float4*)&Bs[r * 36 + g * 4] = b4;
        __syncthreads();
        if (kc + 32 < 128) {
            a4 = *(const float4*)&x[(size_t)(i0 + r) * 128 + kc + 32 + g * 4];
            b4 = *(const float4*)&Ww[(size_t)(kc + 32 + r) * 512 + j0 + g * 4];
        }
#pragma unroll
        for (int kk = 0; kk < 32; kk++) {
            float2 av = *(float2*)&As[kk * 36 + ty * 2];
            float2 bv = *(float2*)&Bs[kk * 36 + tx * 2];
            a00 += av.x * bv.x; a01 += av.x * bv.y;
            a10 += av.y * bv.x; a11 += av.y * bv.y;
        }
        __syncthreads();
    }
    *(float2*)&w[(size_t)(i0 + ty * 2) * 512 + j0 + tx * 2] = make_float2(a00, a01);
    *(float2*)&w[(size_t)(i0 + ty * 2 + 1) * 512 + j0 + tx * 2] = make_float2(a10, a11);
}

// ---- K2: fused PQR + T(j-half) + normp. grid (8, 8, 8): z = h*2+jh. ----
__global__ __launch_bounds__(256, 2) void k_T(const float* __restrict__ w,
                                              float* __restrict__ P,
                                              float* __restrict__ Q,
                                              float* __restrict__ Rt,
                                              float* __restrict__ T,
                                              float* __restrict__ normp) {
    __shared__ __align__(16) float aT[1152];   // [d][i] stride 36
    __shared__ __align__(16) float cT[1152];   // [d][k] stride 36
    __shared__ __align__(16) float bT[1152];   // [d][j] stride 36
    __shared__ __align__(16) float PsT[1152];  // [i][j] stride 36
    __shared__ __align__(16) float RsT[1152];  // [k][j] stride 36
    int h = blockIdx.z >> 1, jh = blockIdx.z & 1;
    int k0 = blockIdx.x * 32, i0 = blockIdx.y * 32;
    int jc0 = jh * 128;
    size_t hb = (size_t)h * 65536;
    int t = threadIdx.x, tx = t & 15, ty = t >> 4, r = t >> 3, g = t & 7;
    const float sc = 0.17677669529663687f;

    float4 av = *(const float4*)&w[(size_t)(i0 + r) * 512 + h * 32 + g * 4];
    aT[(g * 4 + 0) * 36 + r] = av.x; aT[(g * 4 + 1) * 36 + r] = av.y;
    aT[(g * 4 + 2) * 36 + r] = av.z; aT[(g * 4 + 3) * 36 + r] = av.w;
    float4 cv = *(const float4*)&w[(size_t)(k0 + r) * 512 + 256 + h * 32 + g * 4];
    cT[(g * 4 + 0) * 36 + r] = cv.x; cT[(g * 4 + 1) * 36 + r] = cv.y;
    cT[(g * 4 + 2) * 36 + r] = cv.z; cT[(g * 4 + 3) * 36 + r] = cv.w;
    float4 bv = *(const float4*)&w[(size_t)(jc0 + r) * 512 + 128 + h * 32 + g * 4];
    __syncthreads();

    // register-cached fragments (static indices via full unroll)
    float2 a_tx[32], c_tx[32];
#pragma unroll
    for (int d = 0; d < 32; d++) {
        a_tx[d] = *(float2*)&aT[d * 36 + 2 * tx];
        c_tx[d] = *(float2*)&cT[d * 36 + 2 * tx];
    }

    // Q tile: i = 2ty+ii, k = 2tx+kk
    float dq00 = 0, dq01 = 0, dq10 = 0, dq11 = 0;
#pragma unroll
    for (int d = 0; d < 32; d++) {
        float2 a2 = *(float2*)&aT[d * 36 + 2 * ty];
        float2 c2 = c_tx[d];
        dq00 += a2.x * c2.x; dq01 += a2.x * c2.y;
        dq10 += a2.y * c2.x; dq11 += a2.y * c2.y;
    }
    float q00 = __expf(sc * dq00), q01 = __expf(sc * dq01);
    float q10 = __expf(sc * dq10), q11 = __expf(sc * dq11);
    if (jh == 0) {
        *(float2*)&Q[hb + (size_t)(i0 + ty * 2) * 256 + k0 + tx * 2] = make_float2(q00, q01);
        *(float2*)&Q[hb + (size_t)(i0 + ty * 2 + 1) * 256 + k0 + tx * 2] = make_float2(q10, q11);
    }

    const bool wP = (k0 == 0), wR = (blockIdx.y == 0);
    float acc00 = 0, acc01 = 0, acc10 = 0, acc11 = 0;
    for (int jc = jc0; jc < jc0 + 128; jc += 32) {
        bT[(g * 4 + 0) * 36 + r] = bv.x; bT[(g * 4 + 1) * 36 + r] = bv.y;
        bT[(g * 4 + 2) * 36 + r] = bv.z; bT[(g * 4 + 3) * 36 + r] = bv.w;
        __syncthreads();  // A: bT ready, prior PsT/RsT reads done
        if (jc + 32 < jc0 + 128)
            bv = *(const float4*)&w[(size_t)(jc + 32 + r) * 512 + 128 + h * 32 + g * 4];
        // P chunk: j = 2ty+jj, i = 2tx+ii ; R chunk: j = 2ty+jj, k = 2tx+kk
        float dp00 = 0, dp01 = 0, dp10 = 0, dp11 = 0;
        float dr00 = 0, dr01 = 0, dr10 = 0, dr11 = 0;
#pragma unroll
        for (int d = 0; d < 32; d++) {
            float2 b2 = *(float2*)&bT[d * 36 + 2 * ty];
            float2 a2 = a_tx[d];
            float2 c2 = c_tx[d];
            dp00 += b2.x * a2.x; dp01 += b2.x * a2.y;
            dp10 += b2.y * a2.x; dp11 += b2.y * a2.y;
            dr00 += b2.x * c2.x; dr01 += b2.x * c2.y;
            dr10 += b2.y * c2.x; dr11 += b2.y * c2.y;
        }
        float p00 = __expf(sc * dp00), p01 = __expf(sc * dp01);
        float p10 = __expf(sc * dp10), p11 = __expf(sc * dp11);
        float r00 = __expf(sc * dr00), r01 = __expf(sc * dr01);
        float r10 = __expf(sc * dr10), r11 = __expf(sc * dr11);
        // transposed stores: PsT[i][j], RsT[k][j]
        *(float2*)&PsT[(2 * tx + 0) * 36 + 2 * ty] = make_float2(p00, p10);
        *(float2*)&PsT[(2 * tx + 1) * 36 + 2 * ty] = make_float2(p01, p11);
        *(float2*)&RsT[(2 * tx + 0) * 36 + 2 * ty] = make_float2(r00, r10);
        *(float2*)&RsT[(2 * tx + 1) * 36 + 2 * ty] = make_float2(r01, r11);
        if (wP) {
            *(float2*)&P[hb + (size_t)(i0 + tx * 2 + 0) * 256 + jc + ty * 2] = make_float2(p00, p10);
            *(float2*)&P[hb + (size_t)(i0 + tx * 2 + 1) * 256 + jc + ty * 2] = make_float2(p01, p11);
        }
        if (wR) {
            *(float2*)&Rt[hb + (size_t)(k0 + tx * 2 + 0) * 256 + jc + ty * 2] = make_float2(r00, r10);
            *(float2*)&Rt[hb + (size_t)(k0 + tx * 2 + 1) * 256 + jc + ty * 2] = make_float2(r01, r11);
        }
        __syncthreads();  // B: PsT/RsT ready
        // T accumulate: dot along j in float4 quads
#pragma unroll
        for (int q = 0; q < 8; q++) {
            float4 pA = *(float4*)&PsT[(2 * ty + 0) * 36 + 4 * q];
            float4 pB = *(float4*)&PsT[(2 * ty + 1) * 36 + 4 * q];
            float4 rA = *(float4*)&RsT[(2 * tx + 0) * 36 + 4 * q];
            float4 rB = *(float4*)&RsT[(2 * tx + 1) * 36 + 4 * q];
            acc00 += pA.x * rA.x + pA.y * rA.y + pA.z * rA.z + pA.w * rA.w;
            acc01 += pA.x * rB.x + pA.y * rB.y + pA.z * rB.z + pA.w * rB.w;
            acc10 += pB.x * rA.x + pB.y * rA.y + pB.z * rA.z + pB.w * rA.w;
            acc11 += pB.x * rB.x + pB.y * rB.y + pB.z * rB.z + pB.w * rB.w;
        }
    }
    float* Tp = T + (size_t)jh * 262144;
    *(float2*)&Tp[hb + (size_t)(i0 + ty * 2) * 256 + k0 + tx * 2] = make_float2(acc00, acc01);
    *(float2*)&Tp[hb + (size_t)(i0 + ty * 2 + 1) * 256 + k0 + tx * 2] = make_float2(acc10, acc11);
    __syncthreads();
    float* red = PsT;  // [16][34]
    red[ty * 34 + tx * 2]     = q00 * acc00 + q10 * acc10;
    red[ty * 34 + tx * 2 + 1] = q01 * acc01 + q11 * acc11;
    __syncthreads();
    if (t < 32) {
        float s = 0.f;
#pragma unroll
        for (int m = 0; m < 16; m++) s += red[m * 34 + t];
        normp[h * 4096 + (jh * 8 + blockIdx.y) * 256 + k0 + t] = s;
    }
}

// ---- K3: S(k-half) = (Q rn) @ Rt. grid (8, 8, 8): z = h*2+kh. float4 dots. ----
__global__ __launch_bounds__(256, 2) void k_S(const float* __restrict__ Q,
                                              const float* __restrict__ Rt,
                                              const float* __restrict__ normp,
                                              float* __restrict__ S) {
    __shared__ __align__(16) float AsT[1152];  // [i][k] stride 36 (Q*rn)
    __shared__ __align__(16) float BsT[1152];  // [j][k] stride 36
    __shared__ float rn_s[256];
    int h = blockIdx.z >> 1, kh = blockIdx.z & 1;
    int j0 = blockIdx.x * 32, i0 = blockIdx.y * 32;
    int kc0 = kh * 128;
    size_t hb = (size_t)h * 65536;
    int t = threadIdx.x, tx = t & 15, ty = t >> 4, r = t >> 3, g = t & 7;
    {
        float s = 0.f;
#pragma unroll
        for (int ib = 0; ib < 16; ib++) s += normp[h * 4096 + ib * 256 + t];
        rn_s[t] = 1.f / fmaxf(s, 1e-6f);
    }
    float4 a4 = *(const float4*)&Q[hb + (size_t)(i0 + r) * 256 + kc0 + g * 4];
    float4 b4 = *(const float4*)&Rt[hb + (size_t)(kc0 + r) * 256 + j0 + g * 4];
    __syncthreads();  // rn_s ready
    float a00 = 0, a01 = 0, a10 = 0, a11 = 0;
    for (int kc = kc0; kc < kc0 + 128; kc += 32) {
        float4 rn4 = *(float4*)&rn_s[kc + g * 4];
        float4 as4;
        as4.x = a4.x * rn4.x; as4.y = a4.y * rn4.y;
        as4.z = a4.z * rn4.z; as4.w = a4.w * rn4.w;
        *(float4*)&AsT[r * 36 + g * 4] = as4;   // AsT[i=r][k=g*4..]
        BsT[(g * 4 + 0) * 36 + r] = b4.x;       // BsT[j][k=r]
        BsT[(g * 4 + 1) * 36 + r] = b4.y;
        BsT[(g * 4 + 2) * 36 + r] = b4.z;
        BsT[(g * 4 + 3) * 36 + r] = b4.w;
        __syncthreads();
        if (kc + 32 < kc0 + 128) {
            a4 = *(const float4*)&Q[hb + (size_t)(i0 + r) * 256 + kc + 32 + g * 4];
            b4 = *(const float4*)&Rt[hb + (size_t)(kc + 32 + r) * 256 + j0 + g * 4];
        }
#pragma unroll
        for (int q = 0; q < 8; q++) {
            float4 aA = *(float4*)&AsT[(2 * ty + 0) * 36 + 4 * q];
            float4 aB = *(float4*)&AsT[(2 * ty + 1) * 36 + 4 * q];
            float4 bA = *(float4*)&BsT[(2 * tx + 0) * 36 + 4 * q];
            float4 bB = *(float4*)&BsT[(2 * tx + 1) * 36 + 4 * q];
            a00 += aA.x * bA.x + aA.y * bA.y + aA.z * bA.z + aA.w * bA.w;
            a01 += aA.x * bB.x + aA.y * bB.y + aA.z * bB.z + aA.w * bB.w;
            a10 += aB.x * bA.x + aB.y * bA.y + aB.z * bA.z + aB.w * bA.w;
            a11 += aB.x * bB.x + aB.y * bB.y + aB.z * bB.z + aB.w * bB.w;
        }
        __syncthreads();
    }
    float* Sp = S + (size_t)kh * 262144;
    *(float2*)&Sp[hb + (size_t)(i0 + ty * 2) * 256 + j0 + tx * 2] = make_float2(a00, a01);
    *(float2*)&Sp[hb + (size_t)(i0 + ty * 2 + 1) * 256 + j0 + tx * 2] = make_float2(a10, a11);
}

// ---- K4: x1,x2,y + fused projection. grid (64, 4): 4 rows/block. ----
__global__ __launch_bounds__(256) void k_x1x2(
    const float* __restrict__ P, const float* __restrict__ Q,
    const float* __restrict__ S, const float* __restrict__ T,
    const float* __restrict__ normp, const float* __restrict__ w,
    const float* __restrict__ Wp, float* __restrict__ out) {
    int h = blockIdx.y;
    int i0 = blockIdx.x * 4;
    size_t hb = (size_t)h * 65536;
    __shared__ __align__(16) float wp[1024];   // [4][256]; later redx
    __shared__ __align__(16) float wq[1024];   // [4][256]; later redy
    __shared__ __align__(16) float vT[8320];   // [32][260]; later Wps[32][128]
    __shared__ float rn_s[256];
    __shared__ float ys[144];                  // [4][33+]
    int t = threadIdx.x;
    {
        float s = 0.f;
#pragma unroll
        for (int ib = 0; ib < 16; ib++) s += normp[h * 4096 + ib * 256 + t];
        rn_s[t] = 1.f / fmaxf(s, 1e-6f);
    }
    __syncthreads();
    {   // stage wp/wq: one float4 set per thread
        int rr = t >> 6, jj = (t & 63) * 4;
        size_t o = hb + (size_t)(i0 + rr) * 256 + jj;
        float4 p4  = *(const float4*)&P[o];
        float4 s4a = *(const float4*)&S[o];
        float4 s4b = *(const float4*)&S[o + 262144];
        float4 q4  = *(const float4*)&Q[o];
        float4 t4a = *(const float4*)&T[o];
        float4 t4b = *(const float4*)&T[o + 262144];
        float4 rn4 = *(float4*)&rn_s[jj];
        float4 wpv, wqv;
        wpv.x = p4.x * (s4a.x + s4b.x); wpv.y = p4.y * (s4a.y + s4b.y);
        wpv.z = p4.z * (s4a.z + s4b.z); wpv.w = p4.w * (s4a.w + s4b.w);
        wqv.x = q4.x * (t4a.x + t4b.x) * rn4.x;
        wqv.y = q4.y * (t4a.y + t4b.y) * rn4.y;
        wqv.z = q4.z * (t4a.z + t4b.z) * rn4.z;
        wqv.w = q4.w * (t4a.w + t4b.w) * rn4.w;
        *(float4*)&wp[rr * 256 + jj] = wpv;
        *(float4*)&wq[rr * 256 + jj] = wqv;
    }
#pragma unroll
    for (int m = 0; m < 8; m++) {  // stage vT[d][j] (transposed)
        int jj = m * 32 + (t >> 3);
        int dd = (t & 7) * 4;
        float4 v4 = *(const float4*)&w[(size_t)jj * 512 + 384 + h * 32 + dd];
        vT[(dd + 0) * 260 + jj] = v4.x;
        vT[(dd + 1) * 260 + jj] = v4.y;
        vT[(dd + 2) * 260 + jj] = v4.z;
        vT[(dd + 3) * 260 + jj] = v4.w;
    }
    __syncthreads();
    int d = t & 31, rl = (t >> 5) & 3, jh2 = t >> 7;
    int jbase = jh2 * 128;
    float x1 = 0.f, x2 = 0.f;
#pragma unroll
    for (int q = 0; q < 32; q++) {
        int j = jbase + 4 * q;
        float4 wp4 = *(float4*)&wp[rl * 256 + j];
        float4 wq4 = *(float4*)&wq[rl * 256 + j];
        float4 v4  = *(float4*)&vT[d * 260 + j];
        x1 += wp4.x * v4.x + wp4.y * v4.y + wp4.z * v4.z + wp4.w * v4.w;
        x2 += wq4.x * v4.x + wq4.y * v4.y + wq4.z * v4.z + wq4.w * v4.w;
    }
    __syncthreads();  // done reading wp/wq/vT
    float* redx = wp;
    float* redy = wq;
    redx[t] = x1;
    redy[t] = x2;
    float* Wps = vT;  // [32][128]
#pragma unroll
    for (int m = 0; m < 4; m++) {
        int idx = m * 256 + t;
        int k = idx >> 5, n = (idx & 31) * 4;
        *(float4*)&Wps[k * 128 + n] = *(const float4*)&Wp[(size_t)(h * 32 + k) * 128 + n];
    }
    __syncthreads();
    if (t < 128) {
        float x1t = redx[t] + redx[t + 128];
        float x2t = redy[t] + redy[t + 128];
        ys[rl * 33 + d] = x1t * x2t;   // rl = (t>>5)&3, d = t&31 with jh2==0
    }
    __syncthreads();
    int n = t & 127, ti = t >> 7;  // rows ti, ti+2
    float acc0 = 0.f, acc1 = 0.f;
#pragma unroll
    for (int k = 0; k < 32; k++) {
        float wv = Wps[k * 128 + n];
        acc0 += ys[(ti + 0) * 33 + k] * wv;
        acc1 += ys[(ti + 2) * 33 + k] * wv;
    }
    atomicAdd(&out[(size_t)(i0 + ti + 0) * 128 + n], acc0);
    atomicAdd(&out[(size_t)(i0 + ti + 2) * 128 + n], acc1);
}

extern "C" void kernel_launch(void* const* d_in, const int* in_sizes, int n_in,
                              void* d_out, int out_size, void* d_ws, size_t ws_size,
                              hipStream_t stream) {
    const float* x      = (const float*)d_in[0];
    const float* W_w    = (const float*)d_in[1];
    const float* W_proj = (const float*)d_in[2];
    const float* b_proj = (const float*)d_in[3];
    float* out = (float*)d_out;
    float* ws  = (float*)d_ws;

    float* w     = ws + OFF_W;
    float* P     = ws + OFF_P;
    float* Q     = ws + OFF_Q;
    float* Rt    = ws + OFF_RT;
    float* T     = ws + OFF_T;
    float* S     = ws + OFF_S;
    float* normp = ws + OFF_NORMP;

    k_w<<<dim3(16, 8), 256, 0, stream>>>(x, W_w, w, b_proj, out);
    k_T<<<dim3(8, 8, 8), 256, 0, stream>>>(w, P, Q, Rt, T, normp);
    k_S<<<dim3(8, 8, 8), 256, 0, stream>>>(Q, Rt, normp, S);
    k_x1x2<<<dim3(64, 4), 256, 0, stream>>>(P, Q, S, T, normp, w, W_proj, out);
}

// Round 10
// 36.524 us; speedup vs baseline: 1.5132x; 1.0889x over previous
//
#include <hip/hip_runtime.h>
#include <hip/hip_bf16.h>

// B=1, NN=256, C=128, H=4, D=32 — O(N^3) factorization, 3 kernels.
//   k_w:  w = x @ W_w (256x512); also out = bias (for later atomics)
//   k_T:  P,Q,R on the fly; T = P R split along j into 2 halves (T0,T1);
//         Q,P,Rt side-writes; normp partials. 512 blocks, 2/CU.
//   k_x1x2S: per block (4 rows, head h): rn; qs = Q*rn; S rows = qs @ Rt
//         (Rt read once per block, coalesced from L2 — NO LDS staging);
//         wp = P.*S, wq = qs.*(T0+T1); x1 = wp v, x2 = wq v; y = x1.*x2;
//         out += y @ W_proj[h-slice] (atomicAdd, bias-init by k_w).

constexpr size_t OFF_W     = 0;                     // 256*512
constexpr size_t OFF_P     = 131072;                // 4*65536
constexpr size_t OFF_Q     = OFF_P + 262144;
constexpr size_t OFF_RT    = OFF_Q + 262144;        // R^T: [h][k][j]
constexpr size_t OFF_T     = OFF_RT + 262144;       // two j-halves: 2*262144
constexpr size_t OFF_NORMP = OFF_T + 524288;        // 4*16*256 = 16384

// ---- K1: w = x(256x128) @ Ww(128x512), 32x32 tile, prefetch dbuf ----
__global__ __launch_bounds__(256) void k_w(const float* __restrict__ x,
                                           const float* __restrict__ Ww,
                                           float* __restrict__ w,
                                           const float* __restrict__ bp,
                                           float* __restrict__ out) {
    __shared__ __align__(16) float As[1152];  // [k][i]
    __shared__ __align__(16) float Bs[1152];  // [k][j]
    int j0 = blockIdx.x * 32, i0 = blockIdx.y * 32;
    int t = threadIdx.x, tx = t & 15, ty = t >> 4, r = t >> 3, g = t & 7;
    {   // bias-init out: 128 blocks * 256 threads == 32768 == out elements
        int oidx = (blockIdx.y * 16 + blockIdx.x) * 256 + t;
        out[oidx] = bp[oidx & 127];
    }
    float4 a4 = *(const float4*)&x[(size_t)(i0 + r) * 128 + g * 4];
    float4 b4 = *(const float4*)&Ww[(size_t)r * 512 + j0 + g * 4];
    float a00 = 0, a01 = 0, a10 = 0, a11 = 0;
    for (int kc = 0; kc < 128; kc += 32) {
        As[(g * 4 + 0) * 36 + r] = a4.x; As[(g * 4 + 1) * 36 + r] = a4.y;
        As[(g * 4 + 2) * 36 + r] = a4.z; As[(g * 4 + 3) * 36 + r] = a4.w;
        *(float4*)&Bs[r * 36 + g * 4] = b4;
        __syncthreads();
        if (kc + 32 < 128) {
            a4 = *(const float4*)&x[(size_t)(i0 + r) * 128 + kc + 32 + g * 4];
            b4 = *(const float4*)&Ww[(size_t)(kc + 32 + r) * 512 + j0 + g * 4];
        }
#pragma unroll
        for (int kk = 0; kk < 32; kk++) {
            float2 av = *(float2*)&As[kk * 36 + ty * 2];
            float2 bv = *(float2*)&Bs[kk * 36 + tx * 2];
            a00 += av.x * bv.x; a01 += av.x * bv.y;
            a10 += av.y * bv.x; a11 += av.y * bv.y;
        }
        __syncthreads();
    }
    *(float2*)&w[(size_t)(i0 + ty * 2) * 512 + j0 + tx * 2] = make_float2(a00, a01);
    *(float2*)&w[(size_t)(i0 + ty * 2 + 1) * 512 + j0 + tx * 2] = make_float2(a10, a11);
}

// ---- K2: fused PQR + T(j-half) + normp. grid (8, 8, 8): z = h*2+jh. ----
__global__ __launch_bounds__(256, 2) void k_T(const float* __restrict__ w,
                                              float* __restrict__ P,
                                              float* __restrict__ Q,
                                              float* __restrict__ Rt,
                                              float* __restrict__ T,
                                              float* __restrict__ normp) {
    __shared__ __align__(16) float aT[1152];   // [d][i] stride 36
    __shared__ __align__(16) float cT[1152];   // [d][k] stride 36
    __shared__ __align__(16) float bT[1152];   // [d][j] stride 36
    __shared__ __align__(16) float PsT[1152];  // [i][j] stride 36
    __shared__ __align__(16) float RsT[1152];  // [k][j] stride 36
    int h = blockIdx.z >> 1, jh = blockIdx.z & 1;
    int k0 = blockIdx.x * 32, i0 = blockIdx.y * 32;
    int jc0 = jh * 128;
    size_t hb = (size_t)h * 65536;
    int t = threadIdx.x, tx = t & 15, ty = t >> 4, r = t >> 3, g = t & 7;
    const float sc = 0.17677669529663687f;

    float4 av = *(const float4*)&w[(size_t)(i0 + r) * 512 + h * 32 + g * 4];
    aT[(g * 4 + 0) * 36 + r] = av.x; aT[(g * 4 + 1) * 36 + r] = av.y;
    aT[(g * 4 + 2) * 36 + r] = av.z; aT[(g * 4 + 3) * 36 + r] = av.w;
    float4 cv = *(const float4*)&w[(size_t)(k0 + r) * 512 + 256 + h * 32 + g * 4];
    cT[(g * 4 + 0) * 36 + r] = cv.x; cT[(g * 4 + 1) * 36 + r] = cv.y;
    cT[(g * 4 + 2) * 36 + r] = cv.z; cT[(g * 4 + 3) * 36 + r] = cv.w;
    float4 bv = *(const float4*)&w[(size_t)(jc0 + r) * 512 + 128 + h * 32 + g * 4];
    __syncthreads();

    // register-cached fragments (static indices via full unroll)
    float2 a_tx[32], c_tx[32];
#pragma unroll
    for (int d = 0; d < 32; d++) {
        a_tx[d] = *(float2*)&aT[d * 36 + 2 * tx];
        c_tx[d] = *(float2*)&cT[d * 36 + 2 * tx];
    }

    // Q tile: i = 2ty+ii, k = 2tx+kk
    float dq00 = 0, dq01 = 0, dq10 = 0, dq11 = 0;
#pragma unroll
    for (int d = 0; d < 32; d++) {
        float2 a2 = *(float2*)&aT[d * 36 + 2 * ty];
        float2 c2 = c_tx[d];
        dq00 += a2.x * c2.x; dq01 += a2.x * c2.y;
        dq10 += a2.y * c2.x; dq11 += a2.y * c2.y;
    }
    float q00 = __expf(sc * dq00), q01 = __expf(sc * dq01);
    float q10 = __expf(sc * dq10), q11 = __expf(sc * dq11);
    if (jh == 0) {
        *(float2*)&Q[hb + (size_t)(i0 + ty * 2) * 256 + k0 + tx * 2] = make_float2(q00, q01);
        *(float2*)&Q[hb + (size_t)(i0 + ty * 2 + 1) * 256 + k0 + tx * 2] = make_float2(q10, q11);
    }

    const bool wP = (k0 == 0), wR = (blockIdx.y == 0);
    float acc00 = 0, acc01 = 0, acc10 = 0, acc11 = 0;
    for (int jc = jc0; jc < jc0 + 128; jc += 32) {
        bT[(g * 4 + 0) * 36 + r] = bv.x; bT[(g * 4 + 1) * 36 + r] = bv.y;
        bT[(g * 4 + 2) * 36 + r] = bv.z; bT[(g * 4 + 3) * 36 + r] = bv.w;
        __syncthreads();  // A: bT ready, prior PsT/RsT reads done
        if (jc + 32 < jc0 + 128)
            bv = *(const float4*)&w[(size_t)(jc + 32 + r) * 512 + 128 + h * 32 + g * 4];
        // P chunk: j = 2ty+jj, i = 2tx+ii ; R chunk: j = 2ty+jj, k = 2tx+kk
        float dp00 = 0, dp01 = 0, dp10 = 0, dp11 = 0;
        float dr00 = 0, dr01 = 0, dr10 = 0, dr11 = 0;
#pragma unroll
        for (int d = 0; d < 32; d++) {
            float2 b2 = *(float2*)&bT[d * 36 + 2 * ty];
            float2 a2 = a_tx[d];
            float2 c2 = c_tx[d];
            dp00 += b2.x * a2.x; dp01 += b2.x * a2.y;
            dp10 += b2.y * a2.x; dp11 += b2.y * a2.y;
            dr00 += b2.x * c2.x; dr01 += b2.x * c2.y;
            dr10 += b2.y * c2.x; dr11 += b2.y * c2.y;
        }
        float p00 = __expf(sc * dp00), p01 = __expf(sc * dp01);
        float p10 = __expf(sc * dp10), p11 = __expf(sc * dp11);
        float r00 = __expf(sc * dr00), r01 = __expf(sc * dr01);
        float r10 = __expf(sc * dr10), r11 = __expf(sc * dr11);
        // transposed stores: PsT[i][j], RsT[k][j]
        *(float2*)&PsT[(2 * tx + 0) * 36 + 2 * ty] = make_float2(p00, p10);
        *(float2*)&PsT[(2 * tx + 1) * 36 + 2 * ty] = make_float2(p01, p11);
        *(float2*)&RsT[(2 * tx + 0) * 36 + 2 * ty] = make_float2(r00, r10);
        *(float2*)&RsT[(2 * tx + 1) * 36 + 2 * ty] = make_float2(r01, r11);
        if (wP) {
            *(float2*)&P[hb + (size_t)(i0 + tx * 2 + 0) * 256 + jc + ty * 2] = make_float2(p00, p10);
            *(float2*)&P[hb + (size_t)(i0 + tx * 2 + 1) * 256 + jc + ty * 2] = make_float2(p01, p11);
        }
        if (wR) {
            *(float2*)&Rt[hb + (size_t)(k0 + tx * 2 + 0) * 256 + jc + ty * 2] = make_float2(r00, r10);
            *(float2*)&Rt[hb + (size_t)(k0 + tx * 2 + 1) * 256 + jc + ty * 2] = make_float2(r01, r11);
        }
        __syncthreads();  // B: PsT/RsT ready
        // T accumulate: dot along j in float4 quads
#pragma unroll
        for (int q = 0; q < 8; q++) {
            float4 pA = *(float4*)&PsT[(2 * ty + 0) * 36 + 4 * q];
            float4 pB = *(float4*)&PsT[(2 * ty + 1) * 36 + 4 * q];
            float4 rA = *(float4*)&RsT[(2 * tx + 0) * 36 + 4 * q];
            float4 rB = *(float4*)&RsT[(2 * tx + 1) * 36 + 4 * q];
            acc00 += pA.x * rA.x + pA.y * rA.y + pA.z * rA.z + pA.w * rA.w;
            acc01 += pA.x * rB.x + pA.y * rB.y + pA.z * rB.z + pA.w * rB.w;
            acc10 += pB.x * rA.x + pB.y * rA.y + pB.z * rA.z + pB.w * rA.w;
            acc11 += pB.x * rB.x + pB.y * rB.y + pB.z * rB.z + pB.w * rB.w;
        }
    }
    float* Tp = T + (size_t)jh * 262144;
    *(float2*)&Tp[hb + (size_t)(i0 + ty * 2) * 256 + k0 + tx * 2] = make_float2(acc00, acc01);
    *(float2*)&Tp[hb + (size_t)(i0 + ty * 2 + 1) * 256 + k0 + tx * 2] = make_float2(acc10, acc11);
    __syncthreads();
    float* red = PsT;  // [16][34]
    red[ty * 34 + tx * 2]     = q00 * acc00 + q10 * acc10;
    red[ty * 34 + tx * 2 + 1] = q01 * acc01 + q11 * acc11;
    __syncthreads();
    if (t < 32) {
        float s = 0.f;
#pragma unroll
        for (int m = 0; m < 16; m++) s += red[m * 34 + t];
        normp[h * 4096 + (jh * 8 + blockIdx.y) * 256 + k0 + t] = s;
    }
}

// ---- K3: S rows (from L2 Rt) + x1x2 + projection. grid (64, 4). ----
__global__ __launch_bounds__(256) void k_x1x2S(
    const float* __restrict__ P, const float* __restrict__ Q,
    const float* __restrict__ Rt, const float* __restrict__ T,
    const float* __restrict__ normp, const float* __restrict__ w,
    const float* __restrict__ Wp, float* __restrict__ out) {
    int h = blockIdx.y;
    int i0 = blockIdx.x * 4;
    size_t hb = (size_t)h * 65536;
    __shared__ float rn_s[256];
    __shared__ __align__(16) float qs[1024];   // [4][256] = Q*rn
    __shared__ __align__(16) float Ss[1024];   // [4][256] = S rows
    __shared__ __align__(16) float wp[1024];   // [4][256]; later redx
    __shared__ __align__(16) float wq[1024];   // [4][256]; later redy
    __shared__ __align__(16) float vT[8320];   // red[4][4][256] / [32][260] / Wps[32][128]
    __shared__ float ys[144];                  // [4][33+]
    int t = threadIdx.x;
    {
        float s = 0.f;
#pragma unroll
        for (int ib = 0; ib < 16; ib++) s += normp[h * 4096 + ib * 256 + t];
        rn_s[t] = 1.f / fmaxf(s, 1e-6f);
    }
    __syncthreads();
    {   // qs = Q rows * rn
        int row = t >> 6, jq = (t & 63) * 4;
        float4 q4 = *(const float4*)&Q[hb + (size_t)(i0 + row) * 256 + jq];
        float4 rn4 = *(float4*)&rn_s[jq];
        q4.x *= rn4.x; q4.y *= rn4.y; q4.z *= rn4.z; q4.w *= rn4.w;
        *(float4*)&qs[row * 256 + jq] = q4;
    }
    __syncthreads();
    // S partials: thread (jq = t&63 float4-col, kq = t>>6 k-quarter)
    {
        int jq = (t & 63) * 4, kq = t >> 6;
        float4 acc0 = {0, 0, 0, 0}, acc1 = {0, 0, 0, 0};
        float4 acc2 = {0, 0, 0, 0}, acc3 = {0, 0, 0, 0};
#pragma unroll 8
        for (int kk = 0; kk < 64; kk++) {
            int k = kq * 64 + kk;
            float4 r4 = *(const float4*)&Rt[hb + (size_t)k * 256 + jq];
            float q0 = qs[0 * 256 + k], q1 = qs[1 * 256 + k];
            float q2 = qs[2 * 256 + k], q3 = qs[3 * 256 + k];
            acc0.x += q0 * r4.x; acc0.y += q0 * r4.y; acc0.z += q0 * r4.z; acc0.w += q0 * r4.w;
            acc1.x += q1 * r4.x; acc1.y += q1 * r4.y; acc1.z += q1 * r4.z; acc1.w += q1 * r4.w;
            acc2.x += q2 * r4.x; acc2.y += q2 * r4.y; acc2.z += q2 * r4.z; acc2.w += q2 * r4.w;
            acc3.x += q3 * r4.x; acc3.y += q3 * r4.y; acc3.z += q3 * r4.z; acc3.w += q3 * r4.w;
        }
        float* red = vT;  // red[kq][row][j]: 4*4*256 = 4096 floats
        *(float4*)&red[(kq * 4 + 0) * 256 + jq] = acc0;
        *(float4*)&red[(kq * 4 + 1) * 256 + jq] = acc1;
        *(float4*)&red[(kq * 4 + 2) * 256 + jq] = acc2;
        *(float4*)&red[(kq * 4 + 3) * 256 + jq] = acc3;
    }
    __syncthreads();
    {   // reduce 4 k-quarters -> Ss
        int row = t >> 6, jq = (t & 63) * 4;
        float* red = vT;
        float4 s0 = *(float4*)&red[(0 * 4 + row) * 256 + jq];
        float4 s1 = *(float4*)&red[(1 * 4 + row) * 256 + jq];
        float4 s2 = *(float4*)&red[(2 * 4 + row) * 256 + jq];
        float4 s3 = *(float4*)&red[(3 * 4 + row) * 256 + jq];
        float4 sm;
        sm.x = (s0.x + s1.x) + (s2.x + s3.x);
        sm.y = (s0.y + s1.y) + (s2.y + s3.y);
        sm.z = (s0.z + s1.z) + (s2.z + s3.z);
        sm.w = (s0.w + s1.w) + (s2.w + s3.w);
        *(float4*)&Ss[row * 256 + jq] = sm;
    }
    __syncthreads();  // red no longer needed; vT region free
#pragma unroll
    for (int m = 0; m < 8; m++) {  // stage vT[d][j] (transposed)
        int jj = m * 32 + (t >> 3);
        int dd = (t & 7) * 4;
        float4 v4 = *(const float4*)&w[(size_t)jj * 512 + 384 + h * 32 + dd];
        vT[(dd + 0) * 260 + jj] = v4.x;
        vT[(dd + 1) * 260 + jj] = v4.y;
        vT[(dd + 2) * 260 + jj] = v4.z;
        vT[(dd + 3) * 260 + jj] = v4.w;
    }
    {   // wp = P .* S ; wq = qs .* (T0+T1)
        int rr = t >> 6, jj = (t & 63) * 4;
        size_t o = hb + (size_t)(i0 + rr) * 256 + jj;
        float4 p4  = *(const float4*)&P[o];
        float4 t4a = *(const float4*)&T[o];
        float4 t4b = *(const float4*)&T[o + 262144];
        float4 q4  = *(float4*)&qs[rr * 256 + jj];
        float4 s4  = *(float4*)&Ss[rr * 256 + jj];
        float4 wpv, wqv;
        wpv.x = p4.x * s4.x; wpv.y = p4.y * s4.y;
        wpv.z = p4.z * s4.z; wpv.w = p4.w * s4.w;
        wqv.x = q4.x * (t4a.x + t4b.x); wqv.y = q4.y * (t4a.y + t4b.y);
        wqv.z = q4.z * (t4a.z + t4b.z); wqv.w = q4.w * (t4a.w + t4b.w);
        *(float4*)&wp[rr * 256 + jj] = wpv;
        *(float4*)&wq[rr * 256 + jj] = wqv;
    }
    __syncthreads();
    int d = t & 31, rl = (t >> 5) & 3, jh2 = t >> 7;
    int jbase = jh2 * 128;
    float x1 = 0.f, x2 = 0.f;
#pragma unroll
    for (int q = 0; q < 32; q++) {
        int j = jbase + 4 * q;
        float4 wp4 = *(float4*)&wp[rl * 256 + j];
        float4 wq4 = *(float4*)&wq[rl * 256 + j];
        float4 v4  = *(float4*)&vT[d * 260 + j];
        x1 += wp4.x * v4.x + wp4.y * v4.y + wp4.z * v4.z + wp4.w * v4.w;
        x2 += wq4.x * v4.x + wq4.y * v4.y + wq4.z * v4.z + wq4.w * v4.w;
    }
    __syncthreads();  // done reading wp/wq/vT
    float* redx = wp;
    float* redy = wq;
    redx[t] = x1;
    redy[t] = x2;
    float* Wps = vT;  // [32][128]
#pragma unroll
    for (int m = 0; m < 4; m++) {
        int idx = m * 256 + t;
        int k = idx >> 5, n = (idx & 31) * 4;
        *(float4*)&Wps[k * 128 + n] = *(const float4*)&Wp[(size_t)(h * 32 + k) * 128 + n];
    }
    __syncthreads();
    if (t < 128) {
        float x1t = redx[t] + redx[t + 128];
        float x2t = redy[t] + redy[t + 128];
        ys[rl * 33 + d] = x1t * x2t;   // rl = (t>>5)&3, d = t&31 with jh2==0
    }
    __syncthreads();
    int n = t & 127, ti = t >> 7;  // rows ti, ti+2
    float acc0 = 0.f, acc1 = 0.f;
#pragma unroll
    for (int k = 0; k < 32; k++) {
        float wv = Wps[k * 128 + n];
        acc0 += ys[(ti + 0) * 33 + k] * wv;
        acc1 += ys[(ti + 2) * 33 + k] * wv;
    }
    atomicAdd(&out[(size_t)(i0 + ti + 0) * 128 + n], acc0);
    atomicAdd(&out[(size_t)(i0 + ti + 2) * 128 + n], acc1);
}

extern "C" void kernel_launch(void* const* d_in, const int* in_sizes, int n_in,
                              void* d_out, int out_size, void* d_ws, size_t ws_size,
                              hipStream_t stream) {
    const float* x      = (const float*)d_in[0];
    const float* W_w    = (const float*)d_in[1];
    const float* W_proj = (const float*)d_in[2];
    const float* b_proj = (const float*)d_in[3];
    float* out = (float*)d_out;
    float* ws  = (float*)d_ws;

    float* w     = ws + OFF_W;
    float* P     = ws + OFF_P;
    float* Q     = ws + OFF_Q;
    float* Rt    = ws + OFF_RT;
    float* T     = ws + OFF_T;
    float* normp = ws + OFF_NORMP;

    k_w<<<dim3(16, 8), 256, 0, stream>>>(x, W_w, w, b_proj, out);
    k_T<<<dim3(8, 8, 8), 256, 0, stream>>>(w, P, Q, Rt, T, normp);
    k_x1x2S<<<dim3(64, 4), 256, 0, stream>>>(P, Q, Rt, T, normp, w, W_proj, out);
}